// Round 1
// baseline (308.074 us; speedup 1.0000x reference)
//
#include <hip/hip_runtime.h>
#include <hip/hip_bf16.h>
#include <math.h>

// Problem constants (from reference): B=4, S=2048, n_head=32, h_dim=128
// Dtype map (established rounds 0-3): ALL inputs fp32, output fp32.
// (Harness compares in bf16 domain, but buffers are fp32.)
#define SEQ_LEN 2048
#define NROWS (4 * 2048 * 32)      // 262144 head-rows of 128
#define NSTRIPS (NROWS / 16)       // 16384 strips of 16 rows

typedef short bf16x8 __attribute__((ext_vector_type(8)));  // 8 bf16 = 4 VGPR (MFMA A/B frag)
typedef float f32x4 __attribute__((ext_vector_type(4)));   // MFMA C/D frag

__device__ __forceinline__ unsigned short f2bf(float f) {
    union { float f; unsigned int i; } v; v.f = f;
    unsigned int r = v.i + 0x7FFFu + ((v.i >> 16) & 1u);  // round-to-nearest-even
    return (unsigned short)(r >> 16);
}

// ---------------------------------------------------------------------------
// prep: M = A_0 * ... * A_63 * R  (y = x @ M), built in fp32 LDS, rounded to
// bf16, stored pre-swizzled in 16x16x32 B-fragment order WITH the RoPE
// even/odd column permutation folded in:
//   M'[:, n] = M[:, p(n)],  p(n) = n<64 ? 2n : 2(n-64)+1
// so y'[k] = y[2k], y'[64+k] = y[2k+1]  ->  RoPE pairs live in the SAME lane
// (acc[nt] with acc[nt+4]) in the main kernel; no cross-lane pairing needed.
// Fragment order: frag f = kk*8+nt, lane l holds
//   B'[k = kk*32 + (l>>4)*8 + j][n = nt*16 + (l&15)],  j = 0..7
// All 64 cos/sin + pair indices are precomputed IN PARALLEL (threads 0..63)
// before the inherently-serial 64-step Givens chain, so the chain is pure-LDS.
// ---------------------------------------------------------------------------
__global__ void prep_kernel(const float* __restrict__ thetas,
                            const float* __restrict__ pairs,
                            const float* __restrict__ tscale,
                            const float* __restrict__ rotmat,
                            unsigned short* __restrict__ Bsw) {
    __shared__ float M[128][128];   // 64 KB
    __shared__ float Cv[64], Sv[64];
    __shared__ int   Iv[64], Jv[64];
    const int t = threadIdx.x;      // 128 threads, thread t owns column t
    if (t < 64) {                   // parallel trig + index precompute
        const float th = thetas[t] * tscale[0];
        Cv[t] = cosf(th);
        Sv[t] = sinf(th);
        int i = (int)pairs[2 * t];
        int j = (int)pairs[2 * t + 1];
        Iv[t] = min(max(i, 0), 127);
        Jv[t] = min(max(j, 0), 127);
    }
    for (int d = 0; d < 128; ++d) M[d][t] = rotmat[d * 128 + t];
    __syncthreads();
    // Left-mult by A_r for r = 63 down to 0. Givens left-mult touches only
    // rows i,j of M -> column-private per thread, no syncs needed.
    for (int r = 63; r >= 0; --r) {
        const int i = Iv[r], j = Jv[r];
        const float c = Cv[r], s = Sv[r];
        if (i == j) {
            M[i][t] *= c;
        } else {
            const float a = M[i][t], b = M[j][t];
            M[i][t] = c * a - s * b;   // (A M)[i,:] = c*M[i,:] - s*M[j,:]
            M[j][t] = s * a + c * b;   // (A M)[j,:] = s*M[i,:] + c*M[j,:]
        }
    }
    __syncthreads();
    for (int idx = t; idx < 32 * 64; idx += 128) {
        const int f = idx >> 6, lane = idx & 63;
        const int kk = f >> 3, nt = f & 7;
        const int krow = kk * 32 + (lane >> 4) * 8;
        const int n = nt * 16 + (lane & 15);
        const int col = (n < 64) ? (2 * n) : (2 * (n - 64) + 1);  // RoPE perm
        unsigned short* dst = Bsw + (size_t)idx * 8;
#pragma unroll
        for (int j2 = 0; j2 < 8; ++j2) dst[j2] = f2bf(M[krow + j2][col]);
    }
}

// ---------------------------------------------------------------------------
// main: per wave, grid-stride over 16-row strips of x (fp32).
// y' = x_strip(16x128) @ M'(128x128) via 4 K-steps x 8 N-tiles of 16x16x32
// MFMA (x rounded to bf16 via v_cvt_pk_bf16_f32, fp32 accumulate).
// B lives in LDS (32 KB/block, shared by 4 waves) -> VGPR budget ~100 ->
// 4 blocks/CU resident (vs ~1 wave/SIMD when B was register/AGPR-resident).
// Each B fragment is one conflict-free ds_read_b128 (lane-contiguous 1 KB).
// Fused RoPE epilogue with permuted columns: pair (acc[nt], acc[nt+4]) is
// lane-local; out[.., k] = ye*c - yo*s ; out[.., 64+k] = ye*s + yo*c,
// k = nt*16 + (lane&15), angle = s_pos * inv_freq[k]. Non-temporal stores
// (output never re-read; keep x resident in LLC).
// ---------------------------------------------------------------------------
__global__ __launch_bounds__(256, 4) void rope_kernel(
        const float* __restrict__ x,
        const unsigned short* __restrict__ Bsw,
        const float* __restrict__ invfreq,
        float* __restrict__ out) {
    __shared__ f32x4 Blds[2048];           // 32 KB: B fragments, frag-order
    {
        const f32x4* src = (const f32x4*)Bsw;
#pragma unroll
        for (int i = 0; i < 8; ++i)
            Blds[threadIdx.x + 256 * i] = src[threadIdx.x + 256 * i];
    }
    __syncthreads();

    const int lane = threadIdx.x & 63;
    const int wave = (int)(blockIdx.x * (blockDim.x >> 6) + (threadIdx.x >> 6));
    const int nwaves = (int)(gridDim.x * (blockDim.x >> 6));
    const int m = lane & 15;
    const int quad = lane >> 4;
    const bf16x8* Bf = (const bf16x8*)Blds;

    const float invf = invfreq[lane];  // lane k <-> frequency k (64 freqs)

    for (int strip = wave; strip < NSTRIPS; strip += nwaves) {
        const int r0 = strip * 16;
        const float* xrow = x + (size_t)(r0 + m) * 128 + quad * 8;
        f32x4 lo[4], hi[4];
#pragma unroll
        for (int kk = 0; kk < 4; ++kk) {
            lo[kk] = *(const f32x4*)(xrow + kk * 32);
            hi[kk] = *(const f32x4*)(xrow + kk * 32 + 4);
        }

        // all 16 rows of the strip share one sequence position s
        const int s_pos = (r0 >> 5) & (SEQ_LEN - 1);
        float sn_l, cs_l;
        sincosf((float)s_pos * invf, &sn_l, &cs_l);  // lane k: sin/cos freq k

        bf16x8 A[4];
#pragma unroll
        for (int kk = 0; kk < 4; ++kk) {
            union { __hip_bfloat162 h; unsigned int u; } c0, c1, c2, c3;
            c0.h = __float22bfloat162_rn(make_float2(lo[kk][0], lo[kk][1]));
            c1.h = __float22bfloat162_rn(make_float2(lo[kk][2], lo[kk][3]));
            c2.h = __float22bfloat162_rn(make_float2(hi[kk][0], hi[kk][1]));
            c3.h = __float22bfloat162_rn(make_float2(hi[kk][2], hi[kk][3]));
            union { unsigned int u[4]; bf16x8 v; } a;
            a.u[0] = c0.u; a.u[1] = c1.u; a.u[2] = c2.u; a.u[3] = c3.u;
            A[kk] = a.v;
        }

        f32x4 acc[8];
#pragma unroll
        for (int nt = 0; nt < 8; ++nt) acc[nt] = (f32x4){0.f, 0.f, 0.f, 0.f};

#pragma unroll
        for (int kk = 0; kk < 4; ++kk)
#pragma unroll
            for (int nt = 0; nt < 8; ++nt)
                acc[nt] = __builtin_amdgcn_mfma_f32_16x16x32_bf16(
                    A[kk], Bf[(kk * 8 + nt) * 64 + lane], acc[nt], 0, 0, 0);

        // epilogue: C/D layout col = nt*16 + m, row = quad*4 + rr.
        // Permuted B => acc[nt] = y[2k], acc[nt+4] = y[2k+1], k = nt*16+m.
        float* orow = out + (size_t)(r0 + quad * 4) * 128;
#pragma unroll
        for (int nt = 0; nt < 4; ++nt) {
            const int k = nt * 16 + m;
            const float c = __shfl(cs_l, k, 64);
            const float s = __shfl(sn_l, k, 64);
#pragma unroll
            for (int rr = 0; rr < 4; ++rr) {
                const float ye = acc[nt][rr];       // y[2k]
                const float yo = acc[nt + 4][rr];   // y[2k+1]
                __builtin_nontemporal_store(ye * c - yo * s,
                                            &orow[(size_t)rr * 128 + k]);
                __builtin_nontemporal_store(ye * s + yo * c,
                                            &orow[(size_t)rr * 128 + 64 + k]);
            }
        }
    }
}

extern "C" void kernel_launch(void* const* d_in, const int* in_sizes, int n_in,
                              void* d_out, int out_size, void* d_ws, size_t ws_size,
                              hipStream_t stream) {
    const float* x      = (const float*)d_in[0];   // fp32
    const float* thetas = (const float*)d_in[1];   // fp32
    const float* pairs  = (const float*)d_in[2];   // fp32
    const float* tscale = (const float*)d_in[3];   // fp32
    const float* rotmat = (const float*)d_in[4];   // fp32
    const float* invfr  = (const float*)d_in[5];   // fp32
    // d_in[6] = n_head (int, ==32) — baked into constants
    float* out = (float*)d_out;                    // fp32
    unsigned short* Bsw = (unsigned short*)d_ws;   // 32 KB used

    prep_kernel<<<1, 128, 0, stream>>>(thetas, pairs, tscale, rotmat, Bsw);
    rope_kernel<<<2048, 256, 0, stream>>>(x, Bsw, invfr, out);
}

// Round 2
// 304.674 us; speedup vs baseline: 1.0112x; 1.0112x over previous
//
#include <hip/hip_runtime.h>
#include <hip/hip_bf16.h>
#include <math.h>

// Problem constants (from reference): B=4, S=2048, n_head=32, h_dim=128
// Dtype map (established rounds 0-3): ALL inputs fp32, output fp32.
// (Harness compares in bf16 domain, but buffers are fp32.)
#define SEQ_LEN 2048
#define NROWS (4 * 2048 * 32)      // 262144 head-rows of 128
#define NSTRIPS (NROWS / 16)       // 16384 strips of 16 rows

typedef short bf16x8 __attribute__((ext_vector_type(8)));  // 8 bf16 = 4 VGPR (MFMA A/B frag)
typedef float f32x4 __attribute__((ext_vector_type(4)));   // MFMA C/D frag

__device__ __forceinline__ unsigned short f2bf(float f) {
    union { float f; unsigned int i; } v; v.f = f;
    unsigned int r = v.i + 0x7FFFu + ((v.i >> 16) & 1u);  // round-to-nearest-even
    return (unsigned short)(r >> 16);
}

// ---------------------------------------------------------------------------
// prep: M = A_0 * ... * A_63 * R  (y = x @ M), built in fp32 LDS, rounded to
// bf16, stored pre-swizzled in 16x16x32 B-fragment order WITH the RoPE
// even/odd column permutation folded in:
//   M'[:, n] = M[:, p(n)],  p(n) = n<64 ? 2n : 2(n-64)+1
// so y'[k] = y[2k], y'[64+k] = y[2k+1]  ->  RoPE pairs live in the SAME lane
// (acc[nt] with acc[nt+4]) in the main kernel; no cross-lane pairing needed.
// Fragment order: frag f = kk*8+nt, lane l holds
//   B'[k = kk*32 + (l>>4)*8 + j][n = nt*16 + (l&15)],  j = 0..7
// All 64 cos/sin + pair indices are precomputed IN PARALLEL (threads 0..63)
// before the inherently-serial 64-step Givens chain, so the chain is pure-LDS.
// ---------------------------------------------------------------------------
__global__ void prep_kernel(const float* __restrict__ thetas,
                            const float* __restrict__ pairs,
                            const float* __restrict__ tscale,
                            const float* __restrict__ rotmat,
                            unsigned short* __restrict__ Bsw) {
    __shared__ float M[128][128];   // 64 KB
    __shared__ float Cv[64], Sv[64];
    __shared__ int   Iv[64], Jv[64];
    const int t = threadIdx.x;      // 128 threads, thread t owns column t
    if (t < 64) {                   // parallel trig + index precompute
        const float th = thetas[t] * tscale[0];
        Cv[t] = cosf(th);
        Sv[t] = sinf(th);
        int i = (int)pairs[2 * t];
        int j = (int)pairs[2 * t + 1];
        Iv[t] = min(max(i, 0), 127);
        Jv[t] = min(max(j, 0), 127);
    }
    for (int d = 0; d < 128; ++d) M[d][t] = rotmat[d * 128 + t];
    __syncthreads();
    // Left-mult by A_r for r = 63 down to 0. Givens left-mult touches only
    // rows i,j of M -> column-private per thread, no syncs needed.
    for (int r = 63; r >= 0; --r) {
        const int i = Iv[r], j = Jv[r];
        const float c = Cv[r], s = Sv[r];
        if (i == j) {
            M[i][t] *= c;
        } else {
            const float a = M[i][t], b = M[j][t];
            M[i][t] = c * a - s * b;   // (A M)[i,:] = c*M[i,:] - s*M[j,:]
            M[j][t] = s * a + c * b;   // (A M)[j,:] = s*M[i,:] + c*M[j,:]
        }
    }
    __syncthreads();
    for (int idx = t; idx < 32 * 64; idx += 128) {
        const int f = idx >> 6, lane = idx & 63;
        const int kk = f >> 3, nt = f & 7;
        const int krow = kk * 32 + (lane >> 4) * 8;
        const int n = nt * 16 + (lane & 15);
        const int col = (n < 64) ? (2 * n) : (2 * (n - 64) + 1);  // RoPE perm
        unsigned short* dst = Bsw + (size_t)idx * 8;
#pragma unroll
        for (int j2 = 0; j2 < 8; ++j2) dst[j2] = f2bf(M[krow + j2][col]);
    }
}

// ---------------------------------------------------------------------------
// main: per wave, grid-stride over 16-row strips of x (fp32).
// y' = x_strip(16x128) @ M'(128x128) via 4 K-steps x 8 N-tiles of 16x16x32
// MFMA (x rounded to bf16 via v_cvt_pk_bf16_f32, fp32 accumulate).
// B lives in LDS (32 KB/block, shared by 4 waves); each B fragment is one
// conflict-free ds_read_b128 (lane-contiguous 1 KB).
// Fused RoPE epilogue with permuted columns: pair (acc[nt], acc[nt+4]) is
// lane-local; out[.., k] = ye*c - yo*s ; out[.., 64+k] = ye*s + yo*c,
// k = nt*16 + (lane&15), angle = s_pos * inv_freq[k].
// PLAIN stores (round-1 lesson): __builtin_nontemporal_store on this scatter
// pattern bypassed L2 write-combining -> partial-line RMW at HBM ->
// WRITE_SIZE 133->309 MB and +137 MB FETCH. Write-back L2 assembles the
// scattered 64B segments into full lines (round-0 counters: ideal WRITE_SIZE).
// ---------------------------------------------------------------------------
__global__ __launch_bounds__(256, 4) void rope_kernel(
        const float* __restrict__ x,
        const unsigned short* __restrict__ Bsw,
        const float* __restrict__ invfreq,
        float* __restrict__ out) {
    __shared__ f32x4 Blds[2048];           // 32 KB: B fragments, frag-order
    {
        const f32x4* src = (const f32x4*)Bsw;
#pragma unroll
        for (int i = 0; i < 8; ++i)
            Blds[threadIdx.x + 256 * i] = src[threadIdx.x + 256 * i];
    }
    __syncthreads();

    const int lane = threadIdx.x & 63;
    const int wave = (int)(blockIdx.x * (blockDim.x >> 6) + (threadIdx.x >> 6));
    const int nwaves = (int)(gridDim.x * (blockDim.x >> 6));
    const int m = lane & 15;
    const int quad = lane >> 4;
    const bf16x8* Bf = (const bf16x8*)Blds;

    const float invf = invfreq[lane];  // lane k <-> frequency k (64 freqs)

    for (int strip = wave; strip < NSTRIPS; strip += nwaves) {
        const int r0 = strip * 16;
        const float* xrow = x + (size_t)(r0 + m) * 128 + quad * 8;
        f32x4 lo[4], hi[4];
#pragma unroll
        for (int kk = 0; kk < 4; ++kk) {
            lo[kk] = *(const f32x4*)(xrow + kk * 32);
            hi[kk] = *(const f32x4*)(xrow + kk * 32 + 4);
        }

        // all 16 rows of the strip share one sequence position s
        const int s_pos = (r0 >> 5) & (SEQ_LEN - 1);
        float sn_l, cs_l;
        sincosf((float)s_pos * invf, &sn_l, &cs_l);  // lane k: sin/cos freq k

        bf16x8 A[4];
#pragma unroll
        for (int kk = 0; kk < 4; ++kk) {
            union { __hip_bfloat162 h; unsigned int u; } c0, c1, c2, c3;
            c0.h = __float22bfloat162_rn(make_float2(lo[kk][0], lo[kk][1]));
            c1.h = __float22bfloat162_rn(make_float2(lo[kk][2], lo[kk][3]));
            c2.h = __float22bfloat162_rn(make_float2(hi[kk][0], hi[kk][1]));
            c3.h = __float22bfloat162_rn(make_float2(hi[kk][2], hi[kk][3]));
            union { unsigned int u[4]; bf16x8 v; } a;
            a.u[0] = c0.u; a.u[1] = c1.u; a.u[2] = c2.u; a.u[3] = c3.u;
            A[kk] = a.v;
        }

        f32x4 acc[8];
#pragma unroll
        for (int nt = 0; nt < 8; ++nt) acc[nt] = (f32x4){0.f, 0.f, 0.f, 0.f};

#pragma unroll
        for (int kk = 0; kk < 4; ++kk)
#pragma unroll
            for (int nt = 0; nt < 8; ++nt)
                acc[nt] = __builtin_amdgcn_mfma_f32_16x16x32_bf16(
                    A[kk], Bf[(kk * 8 + nt) * 64 + lane], acc[nt], 0, 0, 0);

        // epilogue: C/D layout col = nt*16 + m, row = quad*4 + rr.
        // Permuted B => acc[nt] = y[2k], acc[nt+4] = y[2k+1], k = nt*16+m.
        float* orow = out + (size_t)(r0 + quad * 4) * 128;
#pragma unroll
        for (int nt = 0; nt < 4; ++nt) {
            const int k = nt * 16 + m;
            const float c = __shfl(cs_l, k, 64);
            const float s = __shfl(sn_l, k, 64);
#pragma unroll
            for (int rr = 0; rr < 4; ++rr) {
                const float ye = acc[nt][rr];       // y[2k]
                const float yo = acc[nt + 4][rr];   // y[2k+1]
                orow[(size_t)rr * 128 + k]      = ye * c - yo * s;
                orow[(size_t)rr * 128 + 64 + k] = ye * s + yo * c;
            }
        }
    }
}

extern "C" void kernel_launch(void* const* d_in, const int* in_sizes, int n_in,
                              void* d_out, int out_size, void* d_ws, size_t ws_size,
                              hipStream_t stream) {
    const float* x      = (const float*)d_in[0];   // fp32
    const float* thetas = (const float*)d_in[1];   // fp32
    const float* pairs  = (const float*)d_in[2];   // fp32
    const float* tscale = (const float*)d_in[3];   // fp32
    const float* rotmat = (const float*)d_in[4];   // fp32
    const float* invfr  = (const float*)d_in[5];   // fp32
    // d_in[6] = n_head (int, ==32) — baked into constants
    float* out = (float*)d_out;                    // fp32
    unsigned short* Bsw = (unsigned short*)d_ws;   // 32 KB used

    prep_kernel<<<1, 128, 0, stream>>>(thetas, pairs, tscale, rotmat, Bsw);
    rope_kernel<<<2048, 256, 0, stream>>>(x, Bsw, invfr, out);
}

// Round 3
// 299.764 us; speedup vs baseline: 1.0277x; 1.0164x over previous
//
#include <hip/hip_runtime.h>
#include <hip/hip_bf16.h>
#include <math.h>

// Problem constants (from reference): B=4, S=2048, n_head=32, h_dim=128
// Dtype map (established rounds 0-3): ALL inputs fp32, output fp32.
// (Harness compares in bf16 domain, but buffers are fp32.)
#define SEQ_LEN 2048
#define NROWS (4 * 2048 * 32)      // 262144 head-rows of 128
#define NSTRIPS (NROWS / 16)       // 16384 strips of 16 rows

typedef short bf16x8 __attribute__((ext_vector_type(8)));  // 8 bf16 = 4 VGPR (MFMA A/B frag)
typedef float f32x4 __attribute__((ext_vector_type(4)));   // MFMA C/D frag

__device__ __forceinline__ unsigned short f2bf(float f) {
    union { float f; unsigned int i; } v; v.f = f;
    unsigned int r = v.i + 0x7FFFu + ((v.i >> 16) & 1u);  // round-to-nearest-even
    return (unsigned short)(r >> 16);
}

// ---------------------------------------------------------------------------
// prep: M = A_0 * ... * A_63 * R  (y = x @ M), built in fp32 LDS, rounded to
// bf16, stored pre-swizzled in 16x16x32 B-fragment order with a column
// permutation chosen so the MAIN kernel's C-layout is STORE-CONTIGUOUS and
// RoPE pairs are lane-local:
//   B-slot n = 16*nt + m  <-  y-column src(n) = (nt<4) ? 8m+2*nt
//                                             : 8m+2*(nt-4)+1
// Main kernel then has, at lane (q,m):  acc[nt] = y[2c], acc[nt+4] = y[2c+1]
// with c = 4m+nt — so out cols 4m..4m+3 (and 64+4m..64+4m+3) are lane-local
// CONSECUTIVE floats -> f32x4 stores, every 128B line written whole by ONE
// instruction. (Round-2 lesson: at 16 waves/CU the concurrent partial-line
// set of half-written output lines exceeded the 4MB/XCD L2 -> half-dirty
// evictions -> WRITE_SIZE 2x output + 0.5x write-allocate FETCH. Whole-line
// single-instruction stores eliminate partial lines at any occupancy.)
// Fragment order: frag f = kk*8+nt, lane l holds
//   B'[k = kk*32 + (l>>4)*8 + j][n = nt*16 + (l&15)],  j = 0..7
// All 64 cos/sin + pair indices are precomputed IN PARALLEL (threads 0..63)
// before the inherently-serial 64-step Givens chain, so the chain is pure-LDS.
// ---------------------------------------------------------------------------
__global__ void prep_kernel(const float* __restrict__ thetas,
                            const float* __restrict__ pairs,
                            const float* __restrict__ tscale,
                            const float* __restrict__ rotmat,
                            unsigned short* __restrict__ Bsw) {
    __shared__ float M[128][128];   // 64 KB
    __shared__ float Cv[64], Sv[64];
    __shared__ int   Iv[64], Jv[64];
    const int t = threadIdx.x;      // 128 threads, thread t owns column t
    if (t < 64) {                   // parallel trig + index precompute
        const float th = thetas[t] * tscale[0];
        Cv[t] = cosf(th);
        Sv[t] = sinf(th);
        int i = (int)pairs[2 * t];
        int j = (int)pairs[2 * t + 1];
        Iv[t] = min(max(i, 0), 127);
        Jv[t] = min(max(j, 0), 127);
    }
    for (int d = 0; d < 128; ++d) M[d][t] = rotmat[d * 128 + t];
    __syncthreads();
    // Left-mult by A_r for r = 63 down to 0. Givens left-mult touches only
    // rows i,j of M -> column-private per thread, no syncs needed.
    for (int r = 63; r >= 0; --r) {
        const int i = Iv[r], j = Jv[r];
        const float c = Cv[r], s = Sv[r];
        if (i == j) {
            M[i][t] *= c;
        } else {
            const float a = M[i][t], b = M[j][t];
            M[i][t] = c * a - s * b;   // (A M)[i,:] = c*M[i,:] - s*M[j,:]
            M[j][t] = s * a + c * b;   // (A M)[j,:] = s*M[i,:] + c*M[j,:]
        }
    }
    __syncthreads();
    for (int idx = t; idx < 32 * 64; idx += 128) {
        const int f = idx >> 6, lane = idx & 63;
        const int kk = f >> 3, nt = f & 7;
        const int krow = kk * 32 + (lane >> 4) * 8;
        const int m = lane & 15;
        // store-contiguous + lane-local RoPE-pair permutation
        const int col = (nt < 4) ? (8 * m + 2 * nt) : (8 * m + 2 * (nt - 4) + 1);
        unsigned short* dst = Bsw + (size_t)idx * 8;
#pragma unroll
        for (int j2 = 0; j2 < 8; ++j2) dst[j2] = f2bf(M[krow + j2][col]);
    }
}

// ---------------------------------------------------------------------------
// main: per wave, grid-stride over 16-row strips of x (fp32).
// y' = x_strip(16x128) @ B'(128x128) via 4 K-steps x 8 N-tiles of 16x16x32
// MFMA (x rounded to bf16 via v_cvt_pk_bf16_f32, fp32 accumulate).
// B lives in LDS (32 KB/block, shared by 4 waves); each B fragment is one
// conflict-free ds_read_b128 (lane-contiguous 1 KB).
// Permuted B => lane (q,m): acc[nt][rr] = y[2c], acc[nt+4][rr] = y[2c+1],
// c = 4m+nt, row = r0 + q*4 + rr. RoPE epilogue emits two f32x4 per row:
//   out[row][4m+nt]    = ye*cos(s*invf[c]) - yo*sin(...)
//   out[row][64+4m+nt] = ye*sin(...)       + yo*cos(...)
// Each store instruction covers 4 rows x 256B contiguous -> every 128B HBM
// line written whole by a single instruction (no partial-line RMW at L2).
// ---------------------------------------------------------------------------
__global__ __launch_bounds__(256, 4) void rope_kernel(
        const float* __restrict__ x,
        const unsigned short* __restrict__ Bsw,
        const float* __restrict__ invfreq,
        float* __restrict__ out) {
    __shared__ f32x4 Blds[2048];           // 32 KB: B fragments, frag-order
    {
        const f32x4* src = (const f32x4*)Bsw;
#pragma unroll
        for (int i = 0; i < 8; ++i)
            Blds[threadIdx.x + 256 * i] = src[threadIdx.x + 256 * i];
    }
    __syncthreads();

    const int lane = threadIdx.x & 63;
    const int wave = (int)(blockIdx.x * (blockDim.x >> 6) + (threadIdx.x >> 6));
    const int nwaves = (int)(gridDim.x * (blockDim.x >> 6));
    const int m = lane & 15;
    const int quad = lane >> 4;
    const bf16x8* Bf = (const bf16x8*)Blds;

    const float invf = invfreq[lane];  // lane k <-> frequency k (64 freqs)

    for (int strip = wave; strip < NSTRIPS; strip += nwaves) {
        const int r0 = strip * 16;
        const float* xrow = x + (size_t)(r0 + m) * 128 + quad * 8;
        f32x4 lo[4], hi[4];
#pragma unroll
        for (int kk = 0; kk < 4; ++kk) {
            lo[kk] = *(const f32x4*)(xrow + kk * 32);
            hi[kk] = *(const f32x4*)(xrow + kk * 32 + 4);
        }

        // all 16 rows of the strip share one sequence position s
        const int s_pos = (r0 >> 5) & (SEQ_LEN - 1);
        float sn_l, cs_l;
        sincosf((float)s_pos * invf, &sn_l, &cs_l);  // lane k: sin/cos freq k

        bf16x8 A[4];
#pragma unroll
        for (int kk = 0; kk < 4; ++kk) {
            union { __hip_bfloat162 h; unsigned int u; } c0, c1, c2, c3;
            c0.h = __float22bfloat162_rn(make_float2(lo[kk][0], lo[kk][1]));
            c1.h = __float22bfloat162_rn(make_float2(lo[kk][2], lo[kk][3]));
            c2.h = __float22bfloat162_rn(make_float2(hi[kk][0], hi[kk][1]));
            c3.h = __float22bfloat162_rn(make_float2(hi[kk][2], hi[kk][3]));
            union { unsigned int u[4]; bf16x8 v; } a;
            a.u[0] = c0.u; a.u[1] = c1.u; a.u[2] = c2.u; a.u[3] = c3.u;
            A[kk] = a.v;
        }

        f32x4 acc[8];
#pragma unroll
        for (int nt = 0; nt < 8; ++nt) acc[nt] = (f32x4){0.f, 0.f, 0.f, 0.f};

#pragma unroll
        for (int kk = 0; kk < 4; ++kk)
#pragma unroll
            for (int nt = 0; nt < 8; ++nt)
                acc[nt] = __builtin_amdgcn_mfma_f32_16x16x32_bf16(
                    A[kk], Bf[(kk * 8 + nt) * 64 + lane], acc[nt], 0, 0, 0);

        // epilogue: lane (q,m): acc[nt] = y[2c], acc[nt+4] = y[2c+1], c=4m+nt
        float cs[4], sn[4];
#pragma unroll
        for (int nt = 0; nt < 4; ++nt) {
            cs[nt] = __shfl(cs_l, 4 * m + nt, 64);
            sn[nt] = __shfl(sn_l, 4 * m + nt, 64);
        }
        float* orow = out + (size_t)(r0 + quad * 4) * 128;
#pragma unroll
        for (int rr = 0; rr < 4; ++rr) {
            f32x4 ve, vo;
#pragma unroll
            for (int nt = 0; nt < 4; ++nt) {
                const float ye = acc[nt][rr];       // y[2c]
                const float yo = acc[nt + 4][rr];   // y[2c+1]
                ve[nt] = ye * cs[nt] - yo * sn[nt];
                vo[nt] = ye * sn[nt] + yo * cs[nt];
            }
            *(f32x4*)(orow + (size_t)rr * 128 + 4 * m)      = ve;
            *(f32x4*)(orow + (size_t)rr * 128 + 64 + 4 * m) = vo;
        }
    }
}

extern "C" void kernel_launch(void* const* d_in, const int* in_sizes, int n_in,
                              void* d_out, int out_size, void* d_ws, size_t ws_size,
                              hipStream_t stream) {
    const float* x      = (const float*)d_in[0];   // fp32
    const float* thetas = (const float*)d_in[1];   // fp32
    const float* pairs  = (const float*)d_in[2];   // fp32
    const float* tscale = (const float*)d_in[3];   // fp32
    const float* rotmat = (const float*)d_in[4];   // fp32
    const float* invfr  = (const float*)d_in[5];   // fp32
    // d_in[6] = n_head (int, ==32) — baked into constants
    float* out = (float*)d_out;                    // fp32
    unsigned short* Bsw = (unsigned short*)d_ws;   // 32 KB used

    prep_kernel<<<1, 128, 0, stream>>>(thetas, pairs, tscale, rotmat, Bsw);
    rope_kernel<<<2048, 256, 0, stream>>>(x, Bsw, invfr, out);
}

// Round 4
// 262.976 us; speedup vs baseline: 1.1715x; 1.1399x over previous
//
#include <hip/hip_runtime.h>
#include <hip/hip_bf16.h>
#include <math.h>

// Problem constants (from reference): B=4, S=2048, n_head=32, h_dim=128
// Dtype map (established rounds 0-3): ALL inputs fp32, output fp32.
// (Harness compares in bf16 domain, but buffers are fp32.)
#define SEQ_LEN 2048
#define NROWS (4 * 2048 * 32)      // 262144 head-rows of 128
#define NSTRIPS (NROWS / 16)       // 16384 strips of 16 rows

typedef short bf16x8 __attribute__((ext_vector_type(8)));  // 8 bf16 = 4 VGPR (MFMA A/B frag)
typedef float f32x4 __attribute__((ext_vector_type(4)));   // MFMA C/D frag

__device__ __forceinline__ unsigned short f2bf(float f) {
    union { float f; unsigned int i; } v; v.f = f;
    unsigned int r = v.i + 0x7FFFu + ((v.i >> 16) & 1u);  // round-to-nearest-even
    return (unsigned short)(r >> 16);
}

// ---------------------------------------------------------------------------
// prep: M = A_0 * ... * A_63 * R  (y = x @ M), built in fp32 LDS, rounded to
// bf16, stored pre-swizzled in 16x16x32 B-fragment order with a column
// permutation chosen so the MAIN kernel's C-layout is STORE-CONTIGUOUS and
// RoPE pairs are lane-local:
//   B-slot n = 16*nt + m  <-  y-column src(n) = (nt<4) ? 8m+2*nt
//                                             : 8m+2*(nt-4)+1
// Main kernel then has, at lane (q,m):  acc[nt] = y[2c], acc[nt+4] = y[2c+1]
// with c = 4m+nt — out cols 4m..4m+3 (and 64+...) are lane-local consecutive
// floats -> f32x4 stores, each 128B line written whole by one instruction.
// Round-4: 256 threads; rotmat load is linear-coalesced with unroll-8 MLP
// (was: 128 latency-serial strided loads on a single resident block).
// Givens chain (serial in r, parallel over 128 columns) unchanged.
// ---------------------------------------------------------------------------
__global__ void prep_kernel(const float* __restrict__ thetas,
                            const float* __restrict__ pairs,
                            const float* __restrict__ tscale,
                            const float* __restrict__ rotmat,
                            unsigned short* __restrict__ Bsw) {
    __shared__ float M[128][128];   // 64 KB
    __shared__ float Cv[64], Sv[64];
    __shared__ int   Iv[64], Jv[64];
    const int t = threadIdx.x;      // 256 threads
    if (t < 64) {                   // parallel trig + index precompute
        const float th = thetas[t] * tscale[0];
        Cv[t] = cosf(th);
        Sv[t] = sinf(th);
        int i = (int)pairs[2 * t];
        int j = (int)pairs[2 * t + 1];
        Iv[t] = min(max(i, 0), 127);
        Jv[t] = min(max(j, 0), 127);
    }
    // coalesced load: M[d][c] = rotmat[d*128+c], linear over 16384 floats
    float* Mf = &M[0][0];
#pragma unroll 8
    for (int idx = t; idx < 128 * 128; idx += 256) Mf[idx] = rotmat[idx];
    __syncthreads();
    // Left-mult by A_r for r = 63 down to 0. Givens left-mult touches only
    // rows i,j of M -> column-private per thread (threads 0..127), no syncs.
    if (t < 128) {
        for (int r = 63; r >= 0; --r) {
            const int i = Iv[r], j = Jv[r];
            const float c = Cv[r], s = Sv[r];
            if (i == j) {
                M[i][t] *= c;
            } else {
                const float a = M[i][t], b = M[j][t];
                M[i][t] = c * a - s * b;   // (A M)[i,:] = c*M[i,:] - s*M[j,:]
                M[j][t] = s * a + c * b;   // (A M)[j,:] = s*M[i,:] + c*M[j,:]
            }
        }
    }
    __syncthreads();
    for (int idx = t; idx < 32 * 64; idx += 256) {
        const int f = idx >> 6, lane = idx & 63;
        const int kk = f >> 3, nt = f & 7;
        const int krow = kk * 32 + (lane >> 4) * 8;
        const int m = lane & 15;
        // store-contiguous + lane-local RoPE-pair permutation
        const int col = (nt < 4) ? (8 * m + 2 * nt) : (8 * m + 2 * (nt - 4) + 1);
        unsigned short* dst = Bsw + (size_t)idx * 8;
#pragma unroll
        for (int j2 = 0; j2 < 8; ++j2) dst[j2] = f2bf(M[krow + j2][col]);
    }
}

// ---------------------------------------------------------------------------
// main (round 4): each wave owns exactly TWO strips (sA = wave, sB = wave +
// 8192; 2048 blocks x 4 waves x 2 = 16384 = NSTRIPS). Structure for max MLP:
//   1. issue B-staging as 8x global_load_lds (direct-to-LDS, no VGPR trip)
//   2. issue ALL 16 x-load dwordx4 for BOTH strips (24 loads in flight)
//   3. one __syncthreads (drains vmcnt+lgkmcnt, barrier)
//   4. compute+store strip A, then strip B (A's stores drain under B's MFMA)
// Rationale: R3 counters show 3.94 TB/s effective with VALUBusy 4.7% and
// traffic invariant to store pattern -> request-rate/MLP-limited, not
// BW-saturated. VGPR was 64 -> headroom to hold both strips' inputs.
// Numerics identical to R3 (same per-strip math).
// ---------------------------------------------------------------------------
__global__ __launch_bounds__(256, 4) void rope_kernel(
        const float* __restrict__ x,
        const unsigned short* __restrict__ Bsw,
        const float* __restrict__ invfreq,
        float* __restrict__ out) {
    __shared__ f32x4 Blds[2048];           // 32 KB: B fragments, frag-order
    const int tid = threadIdx.x;
    const int lane = tid & 63;
    const int w = tid >> 6;                // wave 0..3 in block
    {   // direct global->LDS staging: chunk i, wave w covers f32x4 slots
        // [i*256 + w*64, +64): lds dest = uniform base + lane*16 (linear ok)
        const char* gbase = (const char*)Bsw;
#pragma unroll
        for (int i = 0; i < 8; ++i) {
            const int fi = i * 256 + w * 64;
            __builtin_amdgcn_global_load_lds(
                (const __attribute__((address_space(1))) unsigned int*)
                    (gbase + (size_t)(fi + lane) * 16),
                (__attribute__((address_space(3))) unsigned int*)&Blds[fi],
                16, 0, 0);
        }
    }

    const int wave = (int)(blockIdx.x * 4 + w);   // 0..8191
    const int m = lane & 15;
    const int quad = lane >> 4;
    const int sA = wave;
    const int sB = wave + 8192;

    // issue both strips' x loads before the barrier (24 loads in flight)
    const float* xA = x + (size_t)(sA * 16 + m) * 128 + quad * 8;
    const float* xB = x + (size_t)(sB * 16 + m) * 128 + quad * 8;
    f32x4 loA[4], hiA[4], loB[4], hiB[4];
#pragma unroll
    for (int kk = 0; kk < 4; ++kk) {
        loA[kk] = *(const f32x4*)(xA + kk * 32);
        hiA[kk] = *(const f32x4*)(xA + kk * 32 + 4);
    }
#pragma unroll
    for (int kk = 0; kk < 4; ++kk) {
        loB[kk] = *(const f32x4*)(xB + kk * 32);
        hiB[kk] = *(const f32x4*)(xB + kk * 32 + 4);
    }

    const float invf = invfreq[lane];  // lane k <-> frequency k (64 freqs)
    float snA, csA, snB, csB;
    sincosf((float)((sA * 16 >> 5) & (SEQ_LEN - 1)) * invf, &snA, &csA);
    sincosf((float)((sB * 16 >> 5) & (SEQ_LEN - 1)) * invf, &snB, &csB);

    __syncthreads();   // drains staging + x loads, LDS ready

    const bf16x8* Bf = (const bf16x8*)Blds;

#pragma unroll
    for (int half = 0; half < 2; ++half) {
        const int r0 = (half ? sB : sA) * 16;
        const f32x4* lo = half ? loB : loA;
        const f32x4* hi = half ? hiB : hiA;
        const float sn_l = half ? snB : snA;
        const float cs_l = half ? csB : csA;

        bf16x8 A[4];
#pragma unroll
        for (int kk = 0; kk < 4; ++kk) {
            union { __hip_bfloat162 h; unsigned int u; } c0, c1, c2, c3;
            c0.h = __float22bfloat162_rn(make_float2(lo[kk][0], lo[kk][1]));
            c1.h = __float22bfloat162_rn(make_float2(lo[kk][2], lo[kk][3]));
            c2.h = __float22bfloat162_rn(make_float2(hi[kk][0], hi[kk][1]));
            c3.h = __float22bfloat162_rn(make_float2(hi[kk][2], hi[kk][3]));
            union { unsigned int u[4]; bf16x8 v; } a;
            a.u[0] = c0.u; a.u[1] = c1.u; a.u[2] = c2.u; a.u[3] = c3.u;
            A[kk] = a.v;
        }

        f32x4 acc[8];
#pragma unroll
        for (int nt = 0; nt < 8; ++nt) acc[nt] = (f32x4){0.f, 0.f, 0.f, 0.f};

#pragma unroll
        for (int kk = 0; kk < 4; ++kk)
#pragma unroll
            for (int nt = 0; nt < 8; ++nt)
                acc[nt] = __builtin_amdgcn_mfma_f32_16x16x32_bf16(
                    A[kk], Bf[(kk * 8 + nt) * 64 + lane], acc[nt], 0, 0, 0);

        // epilogue: lane (q,m): acc[nt] = y[2c], acc[nt+4] = y[2c+1], c=4m+nt
        float cs[4], sn[4];
#pragma unroll
        for (int nt = 0; nt < 4; ++nt) {
            cs[nt] = __shfl(cs_l, 4 * m + nt, 64);
            sn[nt] = __shfl(sn_l, 4 * m + nt, 64);
        }
        float* orow = out + (size_t)(r0 + quad * 4) * 128;
#pragma unroll
        for (int rr = 0; rr < 4; ++rr) {
            f32x4 ve, vo;
#pragma unroll
            for (int nt = 0; nt < 4; ++nt) {
                const float ye = acc[nt][rr];       // y[2c]
                const float yo = acc[nt + 4][rr];   // y[2c+1]
                ve[nt] = ye * cs[nt] - yo * sn[nt];
                vo[nt] = ye * sn[nt] + yo * cs[nt];
            }
            *(f32x4*)(orow + (size_t)rr * 128 + 4 * m)      = ve;
            *(f32x4*)(orow + (size_t)rr * 128 + 64 + 4 * m) = vo;
        }
    }
}

extern "C" void kernel_launch(void* const* d_in, const int* in_sizes, int n_in,
                              void* d_out, int out_size, void* d_ws, size_t ws_size,
                              hipStream_t stream) {
    const float* x      = (const float*)d_in[0];   // fp32
    const float* thetas = (const float*)d_in[1];   // fp32
    const float* pairs  = (const float*)d_in[2];   // fp32
    const float* tscale = (const float*)d_in[3];   // fp32
    const float* rotmat = (const float*)d_in[4];   // fp32
    const float* invfr  = (const float*)d_in[5];   // fp32
    // d_in[6] = n_head (int, ==32) — baked into constants
    float* out = (float*)d_out;                    // fp32
    unsigned short* Bsw = (unsigned short*)d_ws;   // 32 KB used

    prep_kernel<<<1, 256, 0, stream>>>(thetas, pairs, tscale, rotmat, Bsw);
    rope_kernel<<<2048, 256, 0, stream>>>(x, Bsw, invfr, out);
}

// Round 5
// 261.303 us; speedup vs baseline: 1.1790x; 1.0064x over previous
//
#include <hip/hip_runtime.h>
#include <hip/hip_bf16.h>
#include <math.h>

// Problem constants (from reference): B=4, S=2048, n_head=32, h_dim=128
// Dtype map (established rounds 0-3): ALL inputs fp32, output fp32.
// (Harness compares in bf16 domain, but buffers are fp32.)
#define SEQ_LEN 2048
#define NROWS (4 * 2048 * 32)      // 262144 head-rows of 128
#define NSTRIPS (NROWS / 16)       // 16384 strips of 16 rows

typedef short bf16x8 __attribute__((ext_vector_type(8)));  // 8 bf16 = 4 VGPR (MFMA A/B frag)
typedef float f32x4 __attribute__((ext_vector_type(4)));   // MFMA C/D frag

__device__ __forceinline__ unsigned short f2bf(float f) {
    union { float f; unsigned int i; } v; v.f = f;
    unsigned int r = v.i + 0x7FFFu + ((v.i >> 16) & 1u);  // round-to-nearest-even
    return (unsigned short)(r >> 16);
}

// ---------------------------------------------------------------------------
// prep: M = A_0 * ... * A_63 * R  (y = x @ M), built in fp32 LDS, rounded to
// bf16, stored pre-swizzled in 16x16x32 B-fragment order with a column
// permutation chosen so the MAIN kernel's C-layout is STORE-CONTIGUOUS and
// RoPE pairs are lane-local:
//   B-slot n = 16*nt + m  <-  y-column src(n) = (nt<4) ? 8m+2*nt
//                                             : 8m+2*(nt-4)+1
// Main kernel then has, at lane (q,m):  acc[nt] = y[2c], acc[nt+4] = y[2c+1]
// with c = 4m+nt — out cols 4m..4m+3 (and 64+...) are lane-local consecutive
// floats -> f32x4 stores, each 128B line written whole by one instruction.
// ---------------------------------------------------------------------------
__global__ void prep_kernel(const float* __restrict__ thetas,
                            const float* __restrict__ pairs,
                            const float* __restrict__ tscale,
                            const float* __restrict__ rotmat,
                            unsigned short* __restrict__ Bsw) {
    __shared__ float M[128][128];   // 64 KB
    __shared__ float Cv[64], Sv[64];
    __shared__ int   Iv[64], Jv[64];
    const int t = threadIdx.x;      // 256 threads
    if (t < 64) {                   // parallel trig + index precompute
        const float th = thetas[t] * tscale[0];
        Cv[t] = cosf(th);
        Sv[t] = sinf(th);
        int i = (int)pairs[2 * t];
        int j = (int)pairs[2 * t + 1];
        Iv[t] = min(max(i, 0), 127);
        Jv[t] = min(max(j, 0), 127);
    }
    // coalesced load: M[d][c] = rotmat[d*128+c], linear over 16384 floats
    float* Mf = &M[0][0];
#pragma unroll 8
    for (int idx = t; idx < 128 * 128; idx += 256) Mf[idx] = rotmat[idx];
    __syncthreads();
    // Left-mult by A_r for r = 63 down to 0. Givens left-mult touches only
    // rows i,j of M -> column-private per thread (threads 0..127), no syncs.
    if (t < 128) {
        for (int r = 63; r >= 0; --r) {
            const int i = Iv[r], j = Jv[r];
            const float c = Cv[r], s = Sv[r];
            if (i == j) {
                M[i][t] *= c;
            } else {
                const float a = M[i][t], b = M[j][t];
                M[i][t] = c * a - s * b;   // (A M)[i,:] = c*M[i,:] - s*M[j,:]
                M[j][t] = s * a + c * b;   // (A M)[j,:] = s*M[i,:] + c*M[j,:]
            }
        }
    }
    __syncthreads();
    for (int idx = t; idx < 32 * 64; idx += 256) {
        const int f = idx >> 6, lane = idx & 63;
        const int kk = f >> 3, nt = f & 7;
        const int krow = kk * 32 + (lane >> 4) * 8;
        const int m = lane & 15;
        // store-contiguous + lane-local RoPE-pair permutation
        const int col = (nt < 4) ? (8 * m + 2 * nt) : (8 * m + 2 * (nt - 4) + 1);
        unsigned short* dst = Bsw + (size_t)idx * 8;
#pragma unroll
        for (int j2 = 0; j2 < 8; ++j2) dst[j2] = f2bf(M[krow + j2][col]);
    }
}

// ---------------------------------------------------------------------------
// main (round 5): persistent software-pipelined loop, PINNED prefetch.
// Round-4 post-mortem: VGPR_Count=48 proved the compiler SANK the up-front
// strip-B loads past the barrier (plain loads aren't ordered by
// __syncthreads) -> burst/bubble read stream, 2.45 TB/s effective.
// Fix: 1024 blocks x 4 waves x 4 strips/wave (= 16384 exactly); fully
// unrolled ping-pong where PREFETCH(next) is followed by sched_barrier(0)
// so it CANNOT sink below the current strip's MFMA+store phase. Every
// compute phase runs with 8 loads (8 KB/wave) in flight; 4 blocks/CU
// resident (LDS 4x32KB=128 <= 160KB), ~16 waves/CU.
// Traffic must stay at R4's ideal: FETCH ~66 MB (L3-warm x), WRITE ~131 MB.
// ---------------------------------------------------------------------------
__global__ __launch_bounds__(256, 4) void rope_kernel(
        const float* __restrict__ x,
        const unsigned short* __restrict__ Bsw,
        const float* __restrict__ invfreq,
        float* __restrict__ out) {
    __shared__ f32x4 Blds[2048];           // 32 KB: B fragments, frag-order
    const int tid = threadIdx.x;
    const int lane = tid & 63;
    const int w = tid >> 6;                // wave 0..3 in block
    {   // direct global->LDS staging: chunk i, wave w covers f32x4 slots
        // [i*256 + w*64, +64): lds dest = uniform base + lane*16 (linear ok)
        const char* gbase = (const char*)Bsw;
#pragma unroll
        for (int i = 0; i < 8; ++i) {
            const int fi = i * 256 + w * 64;
            __builtin_amdgcn_global_load_lds(
                (const __attribute__((address_space(1))) unsigned int*)
                    (gbase + (size_t)(fi + lane) * 16),
                (__attribute__((address_space(3))) unsigned int*)&Blds[fi],
                16, 0, 0);
        }
    }

    const int wave = (int)(blockIdx.x * 4 + w);   // 0..4095
    const int m = lane & 15;
    const int quad = lane >> 4;
    const bf16x8* Bf = (const bf16x8*)Blds;
    const float invf = invfreq[lane];  // lane k <-> frequency k (64 freqs)

    const int s0 = wave;
    const int s1 = wave + 4096;
    const int s2 = wave + 8192;
    const int s3 = wave + 12288;

    f32x4 lo0[4], hi0[4], lo1[4], hi1[4];

    auto PREFETCH = [&](f32x4* lo, f32x4* hi, int s) {
        const float* xs = x + (size_t)(s * 16 + m) * 128 + quad * 8;
#pragma unroll
        for (int kk = 0; kk < 4; ++kk) {
            lo[kk] = *(const f32x4*)(xs + kk * 32);
            hi[kk] = *(const f32x4*)(xs + kk * 32 + 4);
        }
    };

    auto COMPUTE = [&](const f32x4* lo, const f32x4* hi, int s) {
        const int r0 = s * 16;
        // all 16 rows of the strip share one sequence position
        const int s_pos = (s >> 1) & (SEQ_LEN - 1);
        float sn_l, cs_l;
        sincosf((float)s_pos * invf, &sn_l, &cs_l);  // lane k: sin/cos freq k

        bf16x8 A[4];
#pragma unroll
        for (int kk = 0; kk < 4; ++kk) {
            union { __hip_bfloat162 h; unsigned int u; } c0, c1, c2, c3;
            c0.h = __float22bfloat162_rn(make_float2(lo[kk][0], lo[kk][1]));
            c1.h = __float22bfloat162_rn(make_float2(lo[kk][2], lo[kk][3]));
            c2.h = __float22bfloat162_rn(make_float2(hi[kk][0], hi[kk][1]));
            c3.h = __float22bfloat162_rn(make_float2(hi[kk][2], hi[kk][3]));
            union { unsigned int u[4]; bf16x8 v; } a;
            a.u[0] = c0.u; a.u[1] = c1.u; a.u[2] = c2.u; a.u[3] = c3.u;
            A[kk] = a.v;
        }

        f32x4 acc[8];
#pragma unroll
        for (int nt = 0; nt < 8; ++nt) acc[nt] = (f32x4){0.f, 0.f, 0.f, 0.f};

#pragma unroll
        for (int kk = 0; kk < 4; ++kk)
#pragma unroll
            for (int nt = 0; nt < 8; ++nt)
                acc[nt] = __builtin_amdgcn_mfma_f32_16x16x32_bf16(
                    A[kk], Bf[(kk * 8 + nt) * 64 + lane], acc[nt], 0, 0, 0);

        // epilogue: lane (q,m): acc[nt] = y[2c], acc[nt+4] = y[2c+1], c=4m+nt
        float cs[4], sn[4];
#pragma unroll
        for (int nt = 0; nt < 4; ++nt) {
            cs[nt] = __shfl(cs_l, 4 * m + nt, 64);
            sn[nt] = __shfl(sn_l, 4 * m + nt, 64);
        }
        float* orow = out + (size_t)(r0 + quad * 4) * 128;
#pragma unroll
        for (int rr = 0; rr < 4; ++rr) {
            f32x4 ve, vo;
#pragma unroll
            for (int nt = 0; nt < 4; ++nt) {
                const float ye = acc[nt][rr];       // y[2c]
                const float yo = acc[nt + 4][rr];   // y[2c+1]
                ve[nt] = ye * cs[nt] - yo * sn[nt];
                vo[nt] = ye * sn[nt] + yo * cs[nt];
            }
            *(f32x4*)(orow + (size_t)rr * 128 + 4 * m)      = ve;
            *(f32x4*)(orow + (size_t)rr * 128 + 64 + 4 * m) = vo;
        }
    };

    PREFETCH(lo0, hi0, s0);
    __syncthreads();                 // B staged (vmcnt+lgkm drained), LDS ready

    PREFETCH(lo1, hi1, s1);
    __builtin_amdgcn_sched_barrier(0);   // pin: loads may not sink below here
    COMPUTE(lo0, hi0, s0);

    PREFETCH(lo0, hi0, s2);
    __builtin_amdgcn_sched_barrier(0);
    COMPUTE(lo1, hi1, s1);

    PREFETCH(lo1, hi1, s3);
    __builtin_amdgcn_sched_barrier(0);
    COMPUTE(lo0, hi0, s2);

    COMPUTE(lo1, hi1, s3);
}

extern "C" void kernel_launch(void* const* d_in, const int* in_sizes, int n_in,
                              void* d_out, int out_size, void* d_ws, size_t ws_size,
                              hipStream_t stream) {
    const float* x      = (const float*)d_in[0];   // fp32
    const float* thetas = (const float*)d_in[1];   // fp32
    const float* pairs  = (const float*)d_in[2];   // fp32
    const float* tscale = (const float*)d_in[3];   // fp32
    const float* rotmat = (const float*)d_in[4];   // fp32
    const float* invfr  = (const float*)d_in[5];   // fp32
    // d_in[6] = n_head (int, ==32) — baked into constants
    float* out = (float*)d_out;                    // fp32
    unsigned short* Bsw = (unsigned short*)d_ws;   // 32 KB used

    prep_kernel<<<1, 256, 0, stream>>>(thetas, pairs, tscale, rotmat, Bsw);
    rope_kernel<<<1024, 256, 0, stream>>>(x, Bsw, invfr, out);
}